// Round 1
// baseline (86.772 us; speedup 1.0000x reference)
//
#include <hip/hip_runtime.h>

// out[b,s,e] = W[e, tokens[b,s]]  — one_hot @ W.T is an embedding gather.
// tokens: (B*S,) int32, W: (EMBED, VOCAB) fp32 row-major, out: (B*S, EMBED) fp32.

#define VOCAB 50257
#define EMBED 1024
#define NTOK  4096   // B*S = 2*2048

__global__ __launch_bounds__(256) void embed_gather_kernel(
    const int* __restrict__ tokens,
    const float* __restrict__ W,
    float* __restrict__ out) {
    const int token_idx = blockIdx.x;          // one block per token
    const int t = tokens[token_idx];           // broadcast scalar load
    const int e0 = threadIdx.x * 4;            // 256 threads * 4 = 1024 = EMBED

    // Column t of W: element e lives at W[e*VOCAB + t] (stride-VOCAB gather).
    const float* __restrict__ col = W + t;
    float4 v;
    v.x = col[(size_t)(e0 + 0) * VOCAB];
    v.y = col[(size_t)(e0 + 1) * VOCAB];
    v.z = col[(size_t)(e0 + 2) * VOCAB];
    v.w = col[(size_t)(e0 + 3) * VOCAB];

    // Coalesced float4 store: out[token_idx, e0..e0+3]
    *reinterpret_cast<float4*>(out + (size_t)token_idx * EMBED + e0) = v;
}

extern "C" void kernel_launch(void* const* d_in, const int* in_sizes, int n_in,
                              void* d_out, int out_size, void* d_ws, size_t ws_size,
                              hipStream_t stream) {
    const int*   tokens = (const int*)d_in[0];   // (B*S,) = 4096 int32
    const float* W      = (const float*)d_in[1]; // (EMBED, VOCAB) fp32
    float*       out    = (float*)d_out;         // (B*S, EMBED) fp32

    embed_gather_kernel<<<NTOK, 256, 0, stream>>>(tokens, W, out);
}